// Round 9
// baseline (164.466 us; speedup 1.0000x reference)
//
#include <hip/hip_runtime.h>

// ---------------------------------------------------------------------------
// AttentionLayer: out = softmax((xWq+bq)(xWk+bk)^T/8 + mask) (xWv+bv)
// B=4, S=2048, D=1024, H=16, Dh=64.  All-bf16 MFMA pipeline, fp32 accum.
// R23: K/V LDS DOUBLE-BUFFER at (256,3) on the R19 body.  R16's dbuf
//      verdict (-5%) was confounded: it ran at (256,2), and ALL (256,2)
//      configs cluster at ~97-100us/20% occ vs (256,3) at ~94/24.7%.
//      This is the single-variable retest: stage(kt+1)->buf^1 issued at
//      top of iteration kt, flies under the whole compute phase, drained
//      by ONE end-of-iteration barrier (16 barriers vs 32).  kt-loop
//      unrolled x2 with LITERAL buffer indices (rule #20).  LDS 65.3KB,
//      2 blocks/CU = 130.6<=160 (residency is register-banded at 2
//      blocks anyway, so LDS doubling is free).  qf back in regs (R22's
//      Q-in-LDS cost ~2us of ds_read in the QK chain).
// LAWS: occupancy bands are POWERS OF 2 (m69): no 3-block band exists;
//      4 waves/SIMD needs total<=128 => spill => occupancy CLOSED (R19/
//      R22: arch 80->72 no change).  R20 zero-LDS 3x worse (L2 latency
//      in MFMA chain, no TLP cover).  R21 KVBLK=256: VGPR 128, -18%.
//      R15 reg-staging SPILLS; R17 T15 -3%; R18 wide-Q SPILLS -32%;
//      7 scheduling variants null/neg; bound(256,4)=>spill; reuse=2=>
//      spill.  Pipe audit: VALU busy 35us (exp2 ~14 irreducible), MFMA
//      27us (floor), wall 94 => serialization at 2 waves/SIMD is the gap.
// ---------------------------------------------------------------------------

typedef __attribute__((ext_vector_type(8))) short bf16x8;
typedef __attribute__((ext_vector_type(4))) float f32x4;
typedef __attribute__((ext_vector_type(16))) float f32x16;

#define LOG2E 1.4426950408889634f

__device__ __forceinline__ ushort f2bf(float f) {
  union { float f; unsigned int u; } x; x.f = f;
  unsigned int r = x.u + 0x7fffu + ((x.u >> 16) & 1u);   // RNE
  return (ushort)(r >> 16);
}

// async global->LDS, 16B per lane; LDS dest = wave-uniform base + lane*16
__device__ __forceinline__ void gload16(const ushort* g, ushort* l) {
  __builtin_amdgcn_global_load_lds(
      (__attribute__((address_space(1))) unsigned int*)(g),
      (__attribute__((address_space(3))) unsigned int*)(l), 16, 0, 0);
}

// ---------------------------------------------------------------------------
// prep: blocks 0..8191 = x->bf16; 8192..11263 = W transpose; 11264 = mask scan
__global__ __launch_bounds__(256) void prep(
    const float* __restrict__ x, ushort* __restrict__ xb,
    const float* __restrict__ Wq, const float* __restrict__ Wk,
    const float* __restrict__ Wv, ushort* __restrict__ WT,
    const int* __restrict__ mask, int* __restrict__ flagw) {
  __shared__ float tile[32][33];
  __shared__ int accum[64];
  const int blk = blockIdx.x, t = threadIdx.x;
  if (blk < 8192) {
    int i = blk * 256 + t;
    float4 v = ((const float4*)x)[i];
    ushort4 o;
    o.x = f2bf(v.x); o.y = f2bf(v.y); o.z = f2bf(v.z); o.w = f2bf(v.w);
    ((ushort4*)xb)[i] = o;
  } else if (blk < 11264) {
    int bb = blk - 8192;
    int z = bb >> 10, rem = bb & 1023, db = rem >> 5, nb = rem & 31;
    const float* W = (z == 0) ? Wq : ((z == 1) ? Wk : Wv);
    int tx = t & 31, ty = t >> 5;   // 32 x 8
#pragma unroll
    for (int i = 0; i < 4; i++) {
      int dl = ty + i * 8;
      tile[dl][tx] = W[(size_t)(db * 32 + dl) * 1024 + nb * 32 + tx];
    }
    __syncthreads();
#pragma unroll
    for (int i = 0; i < 4; i++) {
      int nl = ty + i * 8;
      WT[(size_t)(z * 1024 + nb * 32 + nl) * 1024 + db * 32 + tx] = f2bf(tile[tx][nl]);
    }
  } else {
    if (t < 64) accum[t] = 0;
    __syncthreads();
    int p = t >> 2, j = t & 3;          // p = b*16+kt
    int base = p * 128 + j * 32;
    int s = 0;
#pragma unroll
    for (int i = 0; i < 8; i++) {
      int4 v = *(const int4*)(mask + base + i * 4);
      s += v.x + v.y + v.z + v.w;
    }
    atomicAdd(&accum[p], s);
    __syncthreads();
    if (t < 4) {
      int w = 0;
#pragma unroll
      for (int kt = 0; kt < 16; kt++)
        if (accum[t * 16 + kt] != 128) w |= (1 << kt);
      flagw[t] = w;
    }
  }
}

// ---------------------------------------------------------------------------
// fused QKV GEMM, m97 structure + early-issue staging (R8 version, (256,2)).
// blocks 0..1023: mode0 (Q,K: M=8192 N=2048); 1024..1535: mode1 (V^T).
__global__ __launch_bounds__(256, 2) void gemm_qkv(
    const ushort* __restrict__ xb, const ushort* __restrict__ WT,
    const float* __restrict__ bq, const float* __restrict__ bk,
    const float* __restrict__ bv, ushort* __restrict__ Qg,
    ushort* __restrict__ Kg, ushort* __restrict__ VTg) {
  __shared__ __align__(16) ushort As[128 * 64];
  __shared__ __align__(16) ushort Bs[128 * 64];
  const int t = threadIdx.x, wid = t >> 6, lane = t & 63;
  const int blk = blockIdx.x;
  int mode, mb, nb;
  const ushort *A, *B;
  if (blk < 1024) {
    mode = 0;
    int lin2 = (blk & 7) * 128 + (blk >> 3);   // XCD owns 8 mb-panels
    nb = lin2 & 15; mb = lin2 >> 4;
    A = xb; B = WT;
  } else {
    mode = 1;
    int l = blk - 1024;
    int lin2 = (l & 7) * 64 + (l >> 3);        // XCD owns 8 nb-panels
    mb = lin2 & 7; nb = lin2 >> 3;
    A = WT + (size_t)2048 * 1024; B = xb;
  }
  const ushort* Ab = A + (size_t)mb * 128 * 1024;
  const ushort* Bb = B + (size_t)nb * 128 * 1024;
  const int wr = wid >> 1, wc = wid & 1;

  f32x4 acc[4][4] = {};

  const int srow = lane >> 3;              // 0..7 row-in-8
  const int schunk = (lane & 7) ^ srow;    // pre-swizzled source chunk

  // prologue: issue stage(0)
#pragma unroll
  for (int i = 0; i < 4; i++) {
    int blki = i * 4 + wid;
    int row = blki * 8 + srow;
    int ldso = __builtin_amdgcn_readfirstlane(blki * 512);
    gload16(Ab + (size_t)row * 1024 + schunk * 8, As + ldso);
    gload16(Bb + (size_t)row * 1024 + schunk * 8, Bs + ldso);
  }

  for (int kt = 0; kt < 16; ++kt) {
    __syncthreads();                       // (1) stage(kt) arrived

    bf16x8 af[2][4], bf[2][4];
#pragma unroll
    for (int ks = 0; ks < 2; ks++) {
#pragma unroll
      for (int m = 0; m < 4; m++) {
        int row = wr * 64 + m * 16 + (lane & 15);
        int slot = (ks * 4 + (lane >> 4)) ^ (row & 7);
        af[ks][m] = *(const bf16x8*)(As + row * 64 + slot * 8);
      }
#pragma unroll
      for (int n = 0; n < 4; n++) {
        int row = wc * 64 + n * 16 + (lane & 15);
        int slot = (ks * 4 + (lane >> 4)) ^ (row & 7);
        bf[ks][n] = *(const bf16x8*)(Bs + row * 64 + slot * 8);
      }
    }
    __syncthreads();                       // (2) all fragment reads in regs

    if (kt < 15) {
      const int kof = (kt + 1) * 64 + schunk * 8;
#pragma unroll
      for (int i = 0; i < 4; i++) {
        int blki = i * 4 + wid;
        int row = blki * 8 + srow;
        int ldso = __builtin_amdgcn_readfirstlane(blki * 512);
        gload16(Ab + (size_t)row * 1024 + kof, As + ldso);
        gload16(Bb + (size_t)row * 1024 + kof, Bs + ldso);
      }
    }

#pragma unroll
    for (int ks = 0; ks < 2; ks++)
#pragma unroll
      for (int m = 0; m < 4; m++)
#pragma unroll
        for (int n = 0; n < 4; n++)
          acc[m][n] = __builtin_amdgcn_mfma_f32_16x16x32_bf16(
              af[ks][m], bf[ks][n], acc[m][n], 0, 0, 0);
  }

  // epilogue
#pragma unroll
  for (int m = 0; m < 4; m++) {
#pragma unroll
    for (int n = 0; n < 4; n++) {
      if (mode == 0) {
        int col = nb * 128 + wc * 64 + n * 16 + (lane & 15);  // n: [Q|K] 0..2047
        int wq = col >> 10;                                   // 0=Q 1=K
        float bs = wq ? bk[col & 1023] : bq[col & 1023];
        float scale = wq ? 1.0f : (0.125f * LOG2E);           // fold log2e into Q
        ushort* dst = wq ? Kg : Qg;
        int h = (col >> 6) & 15, d = col & 63;
#pragma unroll
        for (int r = 0; r < 4; r++) {
          int row = mb * 128 + wr * 64 + m * 16 + (lane >> 4) * 4 + r;  // b*2048+s
          int b = row >> 11, s = row & 2047;
          float v = (acc[m][n][r] + bs) * scale;
          dst[((size_t)((b << 4) + h) * 2048 + s) * 64 + d] = f2bf(v);
        }
      } else {
        int col = nb * 128 + wc * 64 + n * 16 + (lane & 15);  // m-index: b*2048+s
        int b = col >> 11, s = col & 2047;
#pragma unroll
        for (int r = 0; r < 4; r++) {
          int p = mb * 128 + wr * 64 + m * 16 + (lane >> 4) * 4 + r;  // h*64+d
          float v = acc[m][n][r] + bv[p];
          int h = p >> 6, d = p & 63;
          VTg[((size_t)((b << 4) + h) * 64 + d) * 2048 + s] = f2bf(v);
        }
      }
    }
  }
}

// ---------------------------------------------------------------------------
// Flash attention (R23 = R19 body + K/V dbuf @ (256,3)): swapped-operand
// 32x32 MFMA, per-kb fused QK->exp->pack->PV, max-free softmax, XCD
// swizzle, pair-interleave LDS mapping, qf in regs.  ONE barrier per kt;
// stage(kt+1) issued at top of iteration kt into buf^1, drained by the
// end-of-iteration barrier after flying under the whole compute phase.
// Tile kt lives in Ks[(kt+1)&1] (prologue: Q->Ks[0], K0->Ks[1], V0->Vs[1]).

#define ATTN_STEP(KT, CUR, NXT)                                                \
  {                                                                            \
    if ((KT) < 15) {                                                           \
      _Pragma("unroll")                                                        \
      for (int i = 0; i < 4; i++) {                                            \
        int blki = i * 4 + wid;                                                \
        int ldso = __builtin_amdgcn_readfirstlane(blki * 512);                 \
        gload16(Kbh + ((KT) + 1) * 8192 + blki * 512 + okl, &Ks[NXT][0] + ldso); \
        gload16(Vbh + blki * 8192 + ((KT) + 1) * 128 + ovl, &Vs[NXT][0] + ldso); \
      }                                                                        \
      if (((fb >> ((KT) + 1)) & 1) && t < 128)                                 \
        maddv[NXT][t] = (1.0f - (float)mask[b * 2048 + ((KT) + 1) * 128 + t])  \
                        * (-10000.0f * LOG2E);                                 \
    }                                                                          \
    const bool msk = ((fb >> (KT)) & 1) != 0;                                  \
    _Pragma("unroll")                                                          \
    for (int kb = 0; kb < 4; kb++) {                                           \
      const ushort* krow = &Ks[CUR][0] + (kb * 16 + prq) * 128;                \
      const f32x16 zz = {};                                                    \
      __builtin_amdgcn_s_setprio(1);                                           \
      bf16x8 kf0 = *(const bf16x8*)(krow + (((0 + hi) | hq8) ^ prq) * 8);      \
      f32x16 a = __builtin_amdgcn_mfma_f32_32x32x16_bf16(kf0, qf[0], zz, 0, 0, 0); \
      bf16x8 kf1 = *(const bf16x8*)(krow + (((2 + hi) | hq8) ^ prq) * 8);      \
      a = __builtin_amdgcn_mfma_f32_32x32x16_bf16(kf1, qf[1], a, 0, 0, 0);     \
      bf16x8 kf2 = *(const bf16x8*)(krow + (((4 + hi) | hq8) ^ prq) * 8);      \
      a = __builtin_amdgcn_mfma_f32_32x32x16_bf16(kf2, qf[2], a, 0, 0, 0);     \
      bf16x8 kf3 = *(const bf16x8*)(krow + (((6 + hi) | hq8) ^ prq) * 8);      \
      a = __builtin_amdgcn_mfma_f32_32x32x16_bf16(kf3, qf[3], a, 0, 0, 0);     \
      __builtin_amdgcn_s_setprio(0);                                           \
      if (msk) {                                                               \
        _Pragma("unroll")                                                      \
        for (int qd = 0; qd < 4; qd++) {                                       \
          f32x4 ma = *(const f32x4*)(&maddv[CUR][0] + kb * 32 + qd * 8 + hi * 4); \
          _Pragma("unroll")                                                    \
          for (int rr = 0; rr < 4; rr++) a[qd * 4 + rr] += ma[rr];             \
        }                                                                      \
      }                                                                        \
      _Pragma("unroll")                                                        \
      for (int w2 = 0; w2 < 2; w2++) {                                         \
        const int o = w2 * 8;                                                  \
        float e0 = __builtin_amdgcn_exp2f(a[o + 0]);                           \
        float e1 = __builtin_amdgcn_exp2f(a[o + 1]);                           \
        float e2 = __builtin_amdgcn_exp2f(a[o + 2]);                           \
        float e3 = __builtin_amdgcn_exp2f(a[o + 3]);                           \
        float e4 = __builtin_amdgcn_exp2f(a[o + 4]);                           \
        float e5 = __builtin_amdgcn_exp2f(a[o + 5]);                           \
        float e6 = __builtin_amdgcn_exp2f(a[o + 6]);                           \
        float e7 = __builtin_amdgcn_exp2f(a[o + 7]);                           \
        l0 += e0; l1 += e1; l0 += e2; l1 += e3;                                \
        l0 += e4; l1 += e5; l0 += e6; l1 += e7;                                \
        unsigned a0, a1, b0, b1;                                               \
        asm("v_cvt_pk_bf16_f32 %0, %1, %2" : "=v"(a0) : "v"(e0), "v"(e1));     \
        asm("v_cvt_pk_bf16_f32 %0, %1, %2" : "=v"(a1) : "v"(e2), "v"(e3));     \
        asm("v_cvt_pk_bf16_f32 %0, %1, %2" : "=v"(b0) : "v"(e4), "v"(e5));     \
        asm("v_cvt_pk_bf16_f32 %0, %1, %2" : "=v"(b1) : "v"(e6), "v"(e7));     \
        asm("v_permlane32_swap_b32 %0, %1" : "+v"(a0), "+v"(b0));              \
        asm("v_permlane32_swap_b32 %0, %1" : "+v"(a1), "+v"(b1));              \
        union { unsigned u[4]; bf16x8 v8; } pu;                                \
        pu.u[0] = a0; pu.u[1] = a1; pu.u[2] = b0; pu.u[3] = b1;                \
        bf16x8 pf = pu.v8;                                                     \
        int w = kb * 2 + w2;                                                   \
        __builtin_amdgcn_s_setprio(1);                                         \
        _Pragma("unroll")                                                      \
        for (int df = 0; df < 2; df++) {                                       \
          int d = df * 32 + l31;                                               \
          int c = (w * 2 + hi) ^ (d & 15);                                     \
          bf16x8 vf = *(const bf16x8*)(&Vs[CUR][0] + d * 128 + c * 8);         \
          cacc[df] = __builtin_amdgcn_mfma_f32_32x32x16_bf16(vf, pf, cacc[df], 0, 0, 0); \
        }                                                                      \
        __builtin_amdgcn_s_setprio(0);                                         \
      }                                                                        \
    }                                                                          \
    if ((KT) < 15) __syncthreads();                                            \
  }

__global__ __launch_bounds__(256, 3) void attn_kernel(
    const ushort* __restrict__ Qg, const ushort* __restrict__ Kg,
    const ushort* __restrict__ VTg, const int* __restrict__ mask,
    const int* __restrict__ flagw, float* __restrict__ out) {
  __shared__ __align__(16) ushort Ks[2][128 * 64];   // 2x16KB
  __shared__ __align__(16) ushort Vs[2][64 * 128];   // 2x16KB
  __shared__ float maddv[2][128];                    // 1KB

  const int t = threadIdx.x, wid = t >> 6, lane = t & 63;
  const int l31 = lane & 31, hi = lane >> 5;
  const int lin = blockIdx.x;
  const int lin2 = (lin & 7) * 128 + (lin >> 3);   // bijective XCD chunking
  const int qb = lin2 & 15, bh = lin2 >> 4;
  const int b = bh >> 4, h = bh & 15;
  const ushort* Qbh = Qg + ((size_t)bh * 2048 + qb * 128) * 64;
  const ushort* Kbh = Kg + (size_t)bh * 2048 * 64;
  const ushort* Vbh = VTg + (size_t)bh * 64 * 2048;

  // ---- staging lane constants (pair-interleave inverse map, collapsed) ----
  const int pr_l = lane >> 4;                 // 0..3 within issue
  const int s_l = lane & 15;
  const int spk = s_l ^ (4 * wid + pr_l);     // shared by Q, K, V staging
  const int okl = 128 * pr_l + (spk >> 3) * 64 + (spk & 7) * 8;
  const int ovl = 2048 * pr_l + spk * 8;

  // ---- fragment-read lane constants ----
  const int prq = l31 >> 1;                   // phys row in 16-row group (0..15)
  const int hq8 = (l31 & 1) << 3;             // halfq<<3

  // ---- prologue: Q->Ks[0], K0->Ks[1], V0->Vs[1], all in flight ----
#pragma unroll
  for (int i = 0; i < 4; i++) {
    int blki = i * 4 + wid;
    int ldso = __builtin_amdgcn_readfirstlane(blki * 512);
    gload16(Qbh + blki * 512 + okl, &Ks[0][0] + ldso);
    gload16(Kbh + blki * 512 + okl, &Ks[1][0] + ldso);
    gload16(Vbh + blki * 8192 + ovl, &Vs[1][0] + ldso);
  }
  const int fb = flagw[b];            // per-tile mask bits (uniform)
  if (((fb >> 0) & 1) && t < 128)
    maddv[1][t] = (1.0f - (float)mask[b * 2048 + t]) * (-10000.0f * LOG2E);
  __syncthreads();                    // Q+K0+V0 staged (implicit vmcnt(0))
  bf16x8 qf[4];
  {
    const ushort* qbase = &Ks[0][0] + (wid * 16 + prq) * 128;   // phys row*256B
#pragma unroll
    for (int ds = 0; ds < 4; ds++) {
      int slot = ((ds * 2 + hi) | hq8) ^ prq;
      qf[ds] = *(const bf16x8*)(qbase + slot * 8);
    }
  }
  __syncthreads();                    // qf reads done before Ks[0] restage

  f32x16 cacc[2] = {};
  float l0 = 0.f, l1 = 0.f;           // persistent psum chains

  // ---- main loop: unrolled x2, literal buffer indices ----
  for (int kt2 = 0; kt2 < 16; kt2 += 2) {
    ATTN_STEP(kt2, 1, 0)              // tile kt2   in Ks[1]; stage -> Ks[0]
    ATTN_STEP(kt2 + 1, 0, 1)          // tile kt2+1 in Ks[0]; stage -> Ks[1]
  }

  // ---- epilogue: l = in-lane chains + cross-hi partner; ctx^T / l ----
  float lrun = l0 + l1;
  lrun += __shfl_xor(lrun, 32);
  float linv = 1.0f / lrun;
  int qg = qb * 128 + wid * 32 + l31;
  float* op = out + ((size_t)(b * 2048 + qg)) * 1024 + h * 64;
#pragma unroll
  for (int df = 0; df < 2; df++)
#pragma unroll
    for (int qd = 0; qd < 4; qd++) {
      f32x4 v;
      v[0] = cacc[df][qd * 4 + 0] * linv;
      v[1] = cacc[df][qd * 4 + 1] * linv;
      v[2] = cacc[df][qd * 4 + 2] * linv;
      v[3] = cacc[df][qd * 4 + 3] * linv;
      *(f32x4*)(op + df * 32 + qd * 8 + hi * 4) = v;
    }
}

// ---------------------------------------------------------------------------
extern "C" void kernel_launch(void* const* d_in, const int* in_sizes, int n_in,
                              void* d_out, int out_size, void* d_ws, size_t ws_size,
                              hipStream_t stream) {
  const float* x  = (const float*)d_in[0];
  const int* mask = (const int*)d_in[1];
  const float* Wq = (const float*)d_in[2];
  const float* bq = (const float*)d_in[3];
  const float* Wk = (const float*)d_in[4];
  const float* bk = (const float*)d_in[5];
  const float* Wv = (const float*)d_in[6];
  const float* bv = (const float*)d_in[7];
  float* out = (float*)d_out;

  char* ws = (char*)d_ws;
  ushort* xb  = (ushort*)(ws);                                  // 16 MB
  ushort* WT  = (ushort*)(ws + (size_t)16777216);               // 6 MB
  ushort* Qg  = (ushort*)(ws + (size_t)23068672);               // 16 MB
  ushort* Kg  = (ushort*)(ws + (size_t)39845888);               // 16 MB
  ushort* VTg = (ushort*)(ws + (size_t)56623104);               // 16 MB
  int*    flg = (int*)(ws + (size_t)73400320);                  // 16 B

  prep<<<dim3(11265), dim3(256), 0, stream>>>(x, xb, Wq, Wk, Wv, WT, mask, flg);
  gemm_qkv<<<dim3(1536), dim3(256), 0, stream>>>(xb, WT, bq, bk, bv, Qg, Kg, VTg);
  attn_kernel<<<dim3(1024), dim3(256), 0, stream>>>(Qg, Kg, VTg, mask, flg, out);
}

// Round 10
// 158.883 us; speedup vs baseline: 1.0351x; 1.0351x over previous
//
#include <hip/hip_runtime.h>

// ---------------------------------------------------------------------------
// AttentionLayer: out = softmax((xWq+bq)(xWk+bk)^T/8 + mask) (xWv+bv)
// B=4, S=2048, D=1024, H=16, Dh=64.  All-bf16 MFMA pipeline, fp32 accum.
// R24: T14 async-STAGE retest at (256,2).  R15's spill was a LAUNCH-BOUNDS
//      ARTIFACT: (256,3) caps total regs at ~170; staging needs ~164-190.
//      At (256,2) cap=256 the 32 staging VGPRs fit (catalog m214 runs this
//      exact technique at 205 VGPR, +17%).  Structure: bar(A) -> issue
//      K/V(kt+1) global->REG -> compute kt (loads fly under ~4-5k cyc) ->
//      bar(B) -> ds_write regs->LDS -> loop.  R19 diet retained.  R15's
//      code was correctness-verified (passed); only the reg fit changes.
// LAWS: dbuf inflates arch regs to 128 at ANY bounds (R21/R23) => closed.
//      Occupancy bands are powers of 2; <=128 total unreachable => 2
//      waves/SIMD structural (R19/R22).  Zero-LDS 3x worse (R20).  Wide-Q
//      spills (R18).  T15 null (R17).  Q-in-LDS -2% (R22).  (256,2) costs
//      ~3-4us vs (256,3) -- T14's +17% must clear that bar.
// ---------------------------------------------------------------------------

typedef __attribute__((ext_vector_type(8))) short bf16x8;
typedef __attribute__((ext_vector_type(4))) float f32x4;
typedef __attribute__((ext_vector_type(16))) float f32x16;

#define LOG2E 1.4426950408889634f

__device__ __forceinline__ ushort f2bf(float f) {
  union { float f; unsigned int u; } x; x.f = f;
  unsigned int r = x.u + 0x7fffu + ((x.u >> 16) & 1u);   // RNE
  return (ushort)(r >> 16);
}

// async global->LDS, 16B per lane; LDS dest = wave-uniform base + lane*16
__device__ __forceinline__ void gload16(const ushort* g, ushort* l) {
  __builtin_amdgcn_global_load_lds(
      (__attribute__((address_space(1))) unsigned int*)(g),
      (__attribute__((address_space(3))) unsigned int*)(l), 16, 0, 0);
}

// ---------------------------------------------------------------------------
// prep: blocks 0..8191 = x->bf16; 8192..11263 = W transpose; 11264 = mask scan
__global__ __launch_bounds__(256) void prep(
    const float* __restrict__ x, ushort* __restrict__ xb,
    const float* __restrict__ Wq, const float* __restrict__ Wk,
    const float* __restrict__ Wv, ushort* __restrict__ WT,
    const int* __restrict__ mask, int* __restrict__ flagw) {
  __shared__ float tile[32][33];
  __shared__ int accum[64];
  const int blk = blockIdx.x, t = threadIdx.x;
  if (blk < 8192) {
    int i = blk * 256 + t;
    float4 v = ((const float4*)x)[i];
    ushort4 o;
    o.x = f2bf(v.x); o.y = f2bf(v.y); o.z = f2bf(v.z); o.w = f2bf(v.w);
    ((ushort4*)xb)[i] = o;
  } else if (blk < 11264) {
    int bb = blk - 8192;
    int z = bb >> 10, rem = bb & 1023, db = rem >> 5, nb = rem & 31;
    const float* W = (z == 0) ? Wq : ((z == 1) ? Wk : Wv);
    int tx = t & 31, ty = t >> 5;   // 32 x 8
#pragma unroll
    for (int i = 0; i < 4; i++) {
      int dl = ty + i * 8;
      tile[dl][tx] = W[(size_t)(db * 32 + dl) * 1024 + nb * 32 + tx];
    }
    __syncthreads();
#pragma unroll
    for (int i = 0; i < 4; i++) {
      int nl = ty + i * 8;
      WT[(size_t)(z * 1024 + nb * 32 + nl) * 1024 + db * 32 + tx] = f2bf(tile[tx][nl]);
    }
  } else {
    if (t < 64) accum[t] = 0;
    __syncthreads();
    int p = t >> 2, j = t & 3;          // p = b*16+kt
    int base = p * 128 + j * 32;
    int s = 0;
#pragma unroll
    for (int i = 0; i < 8; i++) {
      int4 v = *(const int4*)(mask + base + i * 4);
      s += v.x + v.y + v.z + v.w;
    }
    atomicAdd(&accum[p], s);
    __syncthreads();
    if (t < 4) {
      int w = 0;
#pragma unroll
      for (int kt = 0; kt < 16; kt++)
        if (accum[t * 16 + kt] != 128) w |= (1 << kt);
      flagw[t] = w;
    }
  }
}

// ---------------------------------------------------------------------------
// fused QKV GEMM, m97 structure + early-issue staging (R8 version, (256,2)).
// blocks 0..1023: mode0 (Q,K: M=8192 N=2048); 1024..1535: mode1 (V^T).
__global__ __launch_bounds__(256, 2) void gemm_qkv(
    const ushort* __restrict__ xb, const ushort* __restrict__ WT,
    const float* __restrict__ bq, const float* __restrict__ bk,
    const float* __restrict__ bv, ushort* __restrict__ Qg,
    ushort* __restrict__ Kg, ushort* __restrict__ VTg) {
  __shared__ __align__(16) ushort As[128 * 64];
  __shared__ __align__(16) ushort Bs[128 * 64];
  const int t = threadIdx.x, wid = t >> 6, lane = t & 63;
  const int blk = blockIdx.x;
  int mode, mb, nb;
  const ushort *A, *B;
  if (blk < 1024) {
    mode = 0;
    int lin2 = (blk & 7) * 128 + (blk >> 3);   // XCD owns 8 mb-panels
    nb = lin2 & 15; mb = lin2 >> 4;
    A = xb; B = WT;
  } else {
    mode = 1;
    int l = blk - 1024;
    int lin2 = (l & 7) * 64 + (l >> 3);        // XCD owns 8 nb-panels
    mb = lin2 & 7; nb = lin2 >> 3;
    A = WT + (size_t)2048 * 1024; B = xb;
  }
  const ushort* Ab = A + (size_t)mb * 128 * 1024;
  const ushort* Bb = B + (size_t)nb * 128 * 1024;
  const int wr = wid >> 1, wc = wid & 1;

  f32x4 acc[4][4] = {};

  const int srow = lane >> 3;              // 0..7 row-in-8
  const int schunk = (lane & 7) ^ srow;    // pre-swizzled source chunk

  // prologue: issue stage(0)
#pragma unroll
  for (int i = 0; i < 4; i++) {
    int blki = i * 4 + wid;
    int row = blki * 8 + srow;
    int ldso = __builtin_amdgcn_readfirstlane(blki * 512);
    gload16(Ab + (size_t)row * 1024 + schunk * 8, As + ldso);
    gload16(Bb + (size_t)row * 1024 + schunk * 8, Bs + ldso);
  }

  for (int kt = 0; kt < 16; ++kt) {
    __syncthreads();                       // (1) stage(kt) arrived

    bf16x8 af[2][4], bf[2][4];
#pragma unroll
    for (int ks = 0; ks < 2; ks++) {
#pragma unroll
      for (int m = 0; m < 4; m++) {
        int row = wr * 64 + m * 16 + (lane & 15);
        int slot = (ks * 4 + (lane >> 4)) ^ (row & 7);
        af[ks][m] = *(const bf16x8*)(As + row * 64 + slot * 8);
      }
#pragma unroll
      for (int n = 0; n < 4; n++) {
        int row = wc * 64 + n * 16 + (lane & 15);
        int slot = (ks * 4 + (lane >> 4)) ^ (row & 7);
        bf[ks][n] = *(const bf16x8*)(Bs + row * 64 + slot * 8);
      }
    }
    __syncthreads();                       // (2) all fragment reads in regs

    if (kt < 15) {
      const int kof = (kt + 1) * 64 + schunk * 8;
#pragma unroll
      for (int i = 0; i < 4; i++) {
        int blki = i * 4 + wid;
        int row = blki * 8 + srow;
        int ldso = __builtin_amdgcn_readfirstlane(blki * 512);
        gload16(Ab + (size_t)row * 1024 + kof, As + ldso);
        gload16(Bb + (size_t)row * 1024 + kof, Bs + ldso);
      }
    }

#pragma unroll
    for (int ks = 0; ks < 2; ks++)
#pragma unroll
      for (int m = 0; m < 4; m++)
#pragma unroll
        for (int n = 0; n < 4; n++)
          acc[m][n] = __builtin_amdgcn_mfma_f32_16x16x32_bf16(
              af[ks][m], bf[ks][n], acc[m][n], 0, 0, 0);
  }

  // epilogue
#pragma unroll
  for (int m = 0; m < 4; m++) {
#pragma unroll
    for (int n = 0; n < 4; n++) {
      if (mode == 0) {
        int col = nb * 128 + wc * 64 + n * 16 + (lane & 15);  // n: [Q|K] 0..2047
        int wq = col >> 10;                                   // 0=Q 1=K
        float bs = wq ? bk[col & 1023] : bq[col & 1023];
        float scale = wq ? 1.0f : (0.125f * LOG2E);           // fold log2e into Q
        ushort* dst = wq ? Kg : Qg;
        int h = (col >> 6) & 15, d = col & 63;
#pragma unroll
        for (int r = 0; r < 4; r++) {
          int row = mb * 128 + wr * 64 + m * 16 + (lane >> 4) * 4 + r;  // b*2048+s
          int b = row >> 11, s = row & 2047;
          float v = (acc[m][n][r] + bs) * scale;
          dst[((size_t)((b << 4) + h) * 2048 + s) * 64 + d] = f2bf(v);
        }
      } else {
        int col = nb * 128 + wc * 64 + n * 16 + (lane & 15);  // m-index: b*2048+s
        int b = col >> 11, s = col & 2047;
#pragma unroll
        for (int r = 0; r < 4; r++) {
          int p = mb * 128 + wr * 64 + m * 16 + (lane >> 4) * 4 + r;  // h*64+d
          float v = acc[m][n][r] + bv[p];
          int h = p >> 6, d = p & 63;
          VTg[((size_t)((b << 4) + h) * 64 + d) * 2048 + s] = f2bf(v);
        }
      }
    }
  }
}

// ---------------------------------------------------------------------------
// Flash attention (R24 = R19 body + T14 async-STAGE @ (256,2)): swapped-
// operand 32x32 MFMA, single-buffer LDS, per-kb fused QK->exp->pack->PV,
// max-free softmax, XCD swizzle, pair-interleave mapping, R19 diet.
// Per kt: bar(A) -> issue K/V(kt+1) global->REG -> compute kt (loads fly
// under the whole compute phase) -> bar(B) -> ds_write regs->LDS.
__global__ __launch_bounds__(256, 2) void attn_kernel(
    const ushort* __restrict__ Qg, const ushort* __restrict__ Kg,
    const ushort* __restrict__ VTg, const int* __restrict__ mask,
    const int* __restrict__ flagw, float* __restrict__ out) {
  __shared__ __align__(16) ushort Ks[128 * 64];   // 16KB; 64 phys rows x 256B
  __shared__ __align__(16) ushort Vs[64 * 128];   // 16KB; rows=d, 4-bit swizzle
  __shared__ float maddv[128];

  const int t = threadIdx.x, wid = t >> 6, lane = t & 63;
  const int l31 = lane & 31, hi = lane >> 5;
  const int lin = blockIdx.x;
  const int lin2 = (lin & 7) * 128 + (lin >> 3);   // bijective XCD chunking
  const int qb = lin2 & 15, bh = lin2 >> 4;
  const int b = bh >> 4, h = bh & 15;
  const ushort* Qbh = Qg + ((size_t)bh * 2048 + qb * 128) * 64;
  const ushort* Kbh = Kg + (size_t)bh * 2048 * 64;
  const ushort* Vbh = VTg + (size_t)bh * 64 * 2048;

  // ---- staging lane constants (pair-interleave inverse map, collapsed) ----
  const int pr_l = lane >> 4;                 // 0..3 within issue
  const int s_l = lane & 15;
  const int spk = s_l ^ (4 * wid + pr_l);     // shared by Q, K, V staging
  const int okl = 128 * pr_l + (spk >> 3) * 64 + (spk & 7) * 8;
  const int ovl = 2048 * pr_l + spk * 8;
  const int lwr = 512 * wid + lane * 8;       // linear LDS write base (+2048*i)

  // per-lane reg-staging source bases
  const ushort* Kst = Kbh + 512 * wid + okl;  // + kt*8192 + 2048*i
  const ushort* Vst = Vbh + 8192 * wid + ovl; // + 32768*i + kt*128

  // ---- fragment-read lane constants ----
  const int prq = l31 >> 1;                   // phys row in 16-row group (0..15)
  const int hq8 = (l31 & 1) << 3;             // halfq<<3

  // ---- prologue: Q->Ks via gload_lds; K0/V0 -> regs (fly across barrier) --
#pragma unroll
  for (int i = 0; i < 4; i++) {
    int blki = i * 4 + wid;
    int ldso = __builtin_amdgcn_readfirstlane(blki * 512);
    gload16(Qbh + blki * 512 + okl, Ks + ldso);
  }
  bf16x8 kst[4], vst[4];
#pragma unroll
  for (int i = 0; i < 4; i++) kst[i] = *(const bf16x8*)(Kst + 2048 * i);
#pragma unroll
  for (int i = 0; i < 4; i++) vst[i] = *(const bf16x8*)(Vst + 32768 * i);
  const int fb = flagw[b];            // per-tile mask bits (uniform)
  __syncthreads();                    // Q staged
  bf16x8 qf[4];
  {
    const ushort* qbase = Ks + (wid * 16 + prq) * 128;   // phys row *256B
#pragma unroll
    for (int ds = 0; ds < 4; ds++) {
      int slot = ((ds * 2 + hi) | hq8) ^ prq;
      qf[ds] = *(const bf16x8*)(qbase + slot * 8);
    }
  }
  __syncthreads();                    // qf reads done before Ks restage
#pragma unroll
  for (int i = 0; i < 4; i++) *(bf16x8*)(Ks + 2048 * i + lwr) = kst[i];
#pragma unroll
  for (int i = 0; i < 4; i++) *(bf16x8*)(Vs + 2048 * i + lwr) = vst[i];
  if (((fb >> 0) & 1) && t < 128)
    maddv[t] = (1.0f - (float)mask[b * 2048 + t]) * (-10000.0f * LOG2E);

  f32x16 cacc[2] = {};
  float l0 = 0.f, l1 = 0.f;           // persistent psum chains

  for (int kt = 0; kt < 16; ++kt) {
    __syncthreads();                  // (A) tile kt visible in LDS

    // ---- issue stage(kt+1) -> regs; latency hides under kt's compute ----
    if (kt < 15) {
#pragma unroll
      for (int i = 0; i < 4; i++)
        kst[i] = *(const bf16x8*)(Kst + (size_t)(kt + 1) * 8192 + 2048 * i);
#pragma unroll
      for (int i = 0; i < 4; i++)
        vst[i] = *(const bf16x8*)(Vst + 32768 * i + (kt + 1) * 128);
    }
    const bool msk = ((fb >> kt) & 1) != 0;

    // ---- per-kb fused: QK (4 MFMA) -> exp2 -> pack -> PV (4 MFMA) ----
#pragma unroll
    for (int kb = 0; kb < 4; kb++) {
      const ushort* krow = Ks + (kb * 16 + prq) * 128;   // phys row base
      const f32x16 zz = {};
      __builtin_amdgcn_s_setprio(1);
      bf16x8 kf0 = *(const bf16x8*)(krow + (((0 + hi) | hq8) ^ prq) * 8);
      f32x16 a = __builtin_amdgcn_mfma_f32_32x32x16_bf16(kf0, qf[0], zz, 0, 0, 0);
      bf16x8 kf1 = *(const bf16x8*)(krow + (((2 + hi) | hq8) ^ prq) * 8);
      a = __builtin_amdgcn_mfma_f32_32x32x16_bf16(kf1, qf[1], a, 0, 0, 0);
      bf16x8 kf2 = *(const bf16x8*)(krow + (((4 + hi) | hq8) ^ prq) * 8);
      a = __builtin_amdgcn_mfma_f32_32x32x16_bf16(kf2, qf[2], a, 0, 0, 0);
      bf16x8 kf3 = *(const bf16x8*)(krow + (((6 + hi) | hq8) ^ prq) * 8);
      a = __builtin_amdgcn_mfma_f32_32x32x16_bf16(kf3, qf[3], a, 0, 0, 0);
      __builtin_amdgcn_s_setprio(0);

      if (msk) {
#pragma unroll
        for (int qd = 0; qd < 4; qd++) {
          f32x4 ma = *(const f32x4*)(maddv + kb * 32 + qd * 8 + hi * 4);
#pragma unroll
          for (int rr = 0; rr < 4; rr++) a[qd * 4 + rr] += ma[rr];
        }
      }

#pragma unroll
      for (int w2 = 0; w2 < 2; w2++) {
        const int o = w2 * 8;
        float e0 = __builtin_amdgcn_exp2f(a[o + 0]);
        float e1 = __builtin_amdgcn_exp2f(a[o + 1]);
        float e2 = __builtin_amdgcn_exp2f(a[o + 2]);
        float e3 = __builtin_amdgcn_exp2f(a[o + 3]);
        float e4 = __builtin_amdgcn_exp2f(a[o + 4]);
        float e5 = __builtin_amdgcn_exp2f(a[o + 5]);
        float e6 = __builtin_amdgcn_exp2f(a[o + 6]);
        float e7 = __builtin_amdgcn_exp2f(a[o + 7]);
        l0 += e0; l1 += e1; l0 += e2; l1 += e3;
        l0 += e4; l1 += e5; l0 += e6; l1 += e7;
        unsigned a0, a1, b0, b1;
        asm("v_cvt_pk_bf16_f32 %0, %1, %2" : "=v"(a0) : "v"(e0), "v"(e1));
        asm("v_cvt_pk_bf16_f32 %0, %1, %2" : "=v"(a1) : "v"(e2), "v"(e3));
        asm("v_cvt_pk_bf16_f32 %0, %1, %2" : "=v"(b0) : "v"(e4), "v"(e5));
        asm("v_cvt_pk_bf16_f32 %0, %1, %2" : "=v"(b1) : "v"(e6), "v"(e7));
        asm("v_permlane32_swap_b32 %0, %1" : "+v"(a0), "+v"(b0));
        asm("v_permlane32_swap_b32 %0, %1" : "+v"(a1), "+v"(b1));
        union { unsigned u[4]; bf16x8 v8; } pu;
        pu.u[0] = a0; pu.u[1] = a1; pu.u[2] = b0; pu.u[3] = b1;
        bf16x8 pf = pu.v8;
        int w = kb * 2 + w2;
        __builtin_amdgcn_s_setprio(1);
#pragma unroll
        for (int df = 0; df < 2; df++) {
          int d = df * 32 + l31;
          int c = (w * 2 + hi) ^ (d & 15);
          bf16x8 vf = *(const bf16x8*)(Vs + d * 128 + c * 8);
          cacc[df] = __builtin_amdgcn_mfma_f32_32x32x16_bf16(vf, pf, cacc[df], 0, 0, 0);
        }
        __builtin_amdgcn_s_setprio(0);
      }
    }

    // ---- write-late: bar(B) fences reads; ds_write lands tile kt+1 ----
    if (kt < 15) {
      __syncthreads();                // (B)
#pragma unroll
      for (int i = 0; i < 4; i++) *(bf16x8*)(Ks + 2048 * i + lwr) = kst[i];
#pragma unroll
      for (int i = 0; i < 4; i++) *(bf16x8*)(Vs + 2048 * i + lwr) = vst[i];
      if (((fb >> (kt + 1)) & 1) && t < 128)
        maddv[t] = (1.0f - (float)mask[b * 2048 + (kt + 1) * 128 + t]) * (-10000.0f * LOG2E);
    }
  }

  // ---- epilogue: l = in-lane chains + cross-hi partner; ctx^T / l ----
  float lrun = l0 + l1;
  lrun += __shfl_xor(lrun, 32);
  float linv = 1.0f / lrun;
  int qg = qb * 128 + wid * 32 + l31;
  float* op = out + ((size_t)(b * 2048 + qg)) * 1024 + h * 64;
#pragma unroll
  for (int df = 0; df < 2; df++)
#pragma unroll
    for (int qd = 0; qd < 4; qd++) {
      f32x4 v;
      v[0] = cacc[df][qd * 4 + 0] * linv;
      v[1] = cacc[df][qd * 4 + 1] * linv;
      v[2] = cacc[df][qd * 4 + 2] * linv;
      v[3] = cacc[df][qd * 4 + 3] * linv;
      *(f32x4*)(op + df * 32 + qd * 8 + hi * 4) = v;
    }
}

// ---------------------------------------------------------------------------
extern "C" void kernel_launch(void* const* d_in, const int* in_sizes, int n_in,
                              void* d_out, int out_size, void* d_ws, size_t ws_size,
                              hipStream_t stream) {
  const float* x  = (const float*)d_in[0];
  const int* mask = (const int*)d_in[1];
  const float* Wq = (const float*)d_in[2];
  const float* bq = (const float*)d_in[3];
  const float* Wk = (const float*)d_in[4];
  const float* bk = (const float*)d_in[5];
  const float* Wv = (const float*)d_in[6];
  const float* bv = (const float*)d_in[7];
  float* out = (float*)d_out;

  char* ws = (char*)d_ws;
  ushort* xb  = (ushort*)(ws);                                  // 16 MB
  ushort* WT  = (ushort*)(ws + (size_t)16777216);               // 6 MB
  ushort* Qg  = (ushort*)(ws + (size_t)23068672);               // 16 MB
  ushort* Kg  = (ushort*)(ws + (size_t)39845888);               // 16 MB
  ushort* VTg = (ushort*)(ws + (size_t)56623104);               // 16 MB
  int*    flg = (int*)(ws + (size_t)73400320);                  // 16 B

  prep<<<dim3(11265), dim3(256), 0, stream>>>(x, xb, Wq, Wk, Wv, WT, mask, flg);
  gemm_qkv<<<dim3(1536), dim3(256), 0, stream>>>(xb, WT, bq, bk, bv, Qg, Kg, VTg);
  attn_kernel<<<dim3(1024), dim3(256), 0, stream>>>(Qg, Kg, VTg, mask, flg, out);
}